// Round 4
// baseline (663.101 us; speedup 1.0000x reference)
//
#include <hip/hip_runtime.h>
#include <hip/hip_bf16.h>

#define NN 2048
#define BB 8
#define NC 64
#define NTILE 32   // K-tiles of 64
#define NITER 16   // 2 K-tiles per main-loop iteration

typedef __bf16 bf16_8 __attribute__((ext_vector_type(8)));
typedef __bf16 bf16_4 __attribute__((ext_vector_type(4)));
typedef float f32x16 __attribute__((ext_vector_type(16)));

__device__ __forceinline__ void gll16(const void* g, void* l) {
  __builtin_amdgcn_global_load_lds((const __attribute__((address_space(1))) void*)g,
                                   (__attribute__((address_space(3))) void*)l,
                                   16, 0, 0);
}

// fp32 -> bf16 convert + transpose, 16B/lane global reads. (unchanged)
__global__ __launch_bounds__(256)
void k_convert(const float* __restrict__ A, __bf16* __restrict__ Ab, __bf16* __restrict__ At) {
  __shared__ __bf16 tile[64][65];
  int b = blockIdx.z;
  const float* Asrc = A + (size_t)b * NN * NN;
  __bf16* Abd = Ab + (size_t)b * NN * NN;
  __bf16* Atd = At + (size_t)b * NN * NN;
  int r0 = blockIdx.y * 64, c0 = blockIdx.x * 64;
  int row = threadIdx.x >> 4;          // 0..15
  int col4 = (threadIdx.x & 15) * 4;   // 0..60
#pragma unroll
  for (int rr = 0; rr < 64; rr += 16) {
    float4 v = *(const float4*)&Asrc[(size_t)(r0 + row + rr) * NN + c0 + col4];
    bf16_4 hv;
    hv[0] = (__bf16)v.x; hv[1] = (__bf16)v.y; hv[2] = (__bf16)v.z; hv[3] = (__bf16)v.w;
    *(bf16_4*)&Abd[(size_t)(r0 + row + rr) * NN + c0 + col4] = hv;
    tile[row + rr][col4 + 0] = hv[0];
    tile[row + rr][col4 + 1] = hv[1];
    tile[row + rr][col4 + 2] = hv[2];
    tile[row + rr][col4 + 3] = hv[3];
  }
  __syncthreads();
  int row2 = threadIdx.x >> 3;         // 0..31
  int col8 = (threadIdx.x & 7) * 8;    // 0..56
#pragma unroll
  for (int rr = 0; rr < 64; rr += 32) {
    bf16_8 v;
#pragma unroll
    for (int j = 0; j < 8; ++j) v[j] = tile[col8 + j][row2 + rr];
    *(bf16_8*)&Atd[(size_t)(c0 + row2 + rr) * NN + r0 + col8] = v;
  }
}

// C[m,n] = sum_k P[m,k]*Q[n,k], one batch. 256x256 tile, BK=64, 8 waves
// (wm=wave>>2, wn=wave&3), 32x32x16 MFMA, 8-phase counted-vmcnt schedule.
// Static 128 KiB LDS.
//
// CHUNK SWIZZLE g(r) = (r>>1)&7 (was r&7): physical 16B chunk p of row r
// holds logical chunk p ^ g(r). Fragment reads put lanes 0..15 on rows
// base+0..15 at one logical chunk; with g = r&7 the chunk pattern repeats
// every 8 rows -> 2 lanes per 16B slot in each 16-lane group (+4 conflict
// cyc/read measured, ~2x LDS time at 256B/clk). g = (r>>1)&7 gives
// same-parity rows distinct chunks; row-parity bit (16B slot high/low bank
// half) completes full 32x8B-bank coverage per 16-lane group.
//
// B-register-cached schedule (24 b128/wave/K-tile):
//   q0: read A-h0 (8)            ; MFMA acc[0..1][0] = A0 x B0 (bfr[0] regs)
//   q1: read B-h1 (4) -> bfr[1]  ; MFMA acc[0..1][1] = A0 x B1
//   q2: read A-h1 (8)            ; MFMA acc[2..3][1] = A1 x B1 (bfr[1] regs)
//   q3: reg-only MFMA acc[2..3][0] = A1 x B0; then PREFETCH next tile's
//       B-h0 from the OTHER buffer (valid after this phase's vmcnt+barrier)
// Stage schedule (overwrite strictly after the barrier following the
// region's last read; loads/phase = 0,4,2,2,0,4,2,2):
//   p1: A-h0 + B-h0 -> buf0 (tile 2it+2)   p2: B-h1 -> buf0   p3: A-h1 -> buf0
//   p5: A-h0 + B-h0 -> buf1 (tile 2it+3)   p6: B-h1 -> buf1   p7: A-h1 -> buf1
// vmcnt(8) once per K-tile at q3. Never drains to 0 in the main loop.
__device__ __forceinline__
void gemm_body256(const __bf16* __restrict__ Pb, const __bf16* __restrict__ Qb,
                  __bf16* __restrict__ Cb, __bf16* __restrict__ Ctb,
                  __bf16* smem, int tmBlk, int tnBlk) {
  __bf16 (*As)[256][64] = (__bf16(*)[256][64])smem;            // 2 x 32 KB
  __bf16 (*Bs)[256][64] = (__bf16(*)[256][64])(smem + 32768);  // 2 x 32 KB
  const int tid = threadIdx.x;
  const int wave = tid >> 6, lane = tid & 63;
  const int wm = wave >> 2, wn = wave & 3;
  const int tm = tmBlk * 256, tn = tnBlk * 256;
  const int am = lane & 31, ah = lane >> 5;
  const int rx = (am >> 1) & 7;   // read-side swizzle g(row)=(row>>1)&7

  // staging geometry: each STAGE region-call covers rows [base+wave*8,
  // base+wave*8+8) x 8 chunks via 64 lanes; LDS dest linear (lane*16B).
  // Source chunk pre-swizzled: physical chunk p = lane&7 at row
  // base+wave*8+(lane>>3) must hold logical chunk p ^ g(row);
  // g(row) = (row>>1)&7 = ((wave&1)*4 + (lane>>4)) & 7 here.
  const int sr = lane >> 3;
  const int sc = (lane & 7) ^ (((wave & 1) * 4 + (lane >> 4)) & 7);
  const __bf16* srcA = Pb + (size_t)(tm + wave * 8 + sr) * NN + sc * 8;
  const __bf16* srcB = Qb + (size_t)(tn + wave * 8 + sr) * NN + sc * 8;

#define STAGE(Tc_, s_, bufT_)                                                  \
  do {                                                                         \
    if ((s_) == 0) { /* A h0 */                                                \
      const __bf16* s0 = srcA + (size_t)(Tc_) * 64;                            \
      gll16(s0,                   &As[bufT_][wave * 8][0]);                    \
      gll16(s0 + (size_t)64 * NN, &As[bufT_][64 + wave * 8][0]);               \
    } else if ((s_) == 1) { /* B h1 */                                         \
      const __bf16* s0 = srcB + (size_t)128 * NN + (size_t)(Tc_) * 64;         \
      gll16(s0,                   &Bs[bufT_][128 + wave * 8][0]);              \
      gll16(s0 + (size_t)64 * NN, &Bs[bufT_][192 + wave * 8][0]);              \
    } else if ((s_) == 2) { /* A h1 */                                         \
      const __bf16* s0 = srcA + (size_t)128 * NN + (size_t)(Tc_) * 64;         \
      gll16(s0,                   &As[bufT_][128 + wave * 8][0]);              \
      gll16(s0 + (size_t)64 * NN, &As[bufT_][192 + wave * 8][0]);              \
    } else { /* B h0 */                                                        \
      const __bf16* s0 = srcB + (size_t)(Tc_) * 64;                            \
      gll16(s0,                   &Bs[bufT_][wave * 8][0]);                    \
      gll16(s0 + (size_t)64 * NN, &Bs[bufT_][64 + wave * 8][0]);               \
    }                                                                          \
  } while (0)

  // prologue: tile0 -> buf0 (8 loads), tile1 -> buf1 (8 loads).
  // vmcnt(8) -> buf0 fully landed (8 newest outstanding = buf1's).
  STAGE(0, 0, 0); STAGE(0, 3, 0); STAGE(0, 2, 0); STAGE(0, 1, 0);
  STAGE(1, 0, 1); STAGE(1, 3, 1); STAGE(1, 2, 1); STAGE(1, 1, 1);
  asm volatile("s_waitcnt vmcnt(8)" ::: "memory");
  __builtin_amdgcn_s_barrier();

  f32x16 acc[4][2] = {};
  bf16_8 af[2][4], bfr[2][4];

  // prefetch bfr[0] for tile0 (buf0 valid)
  {
    const int rb0 = wn * 32 + am;
#pragma unroll
    for (int ks = 0; ks < 4; ++ks)
      bfr[0][ks] = *(const bf16_8*)&Bs[0][rb0][((2 * ks + ah) ^ rx) * 8];
  }

  for (int it = 0; it < NITER; ++it) {
#pragma unroll
    for (int p = 0; p < 8; ++p) {
      const int q = p & 3;
      const int rbuf = p >> 2;                      // read buffer (static)
      const int i0 = (q >> 1) * 2;                  // im base of quadrant
      const int in = (q == 1 || q == 2) ? 1 : 0;    // B half (register bank)
      // ds reads for this phase
      if (q == 0) {
#pragma unroll
        for (int i = 0; i < 2; ++i) {
          const int ra = (2 * i + wm) * 32 + am;
#pragma unroll
          for (int ks = 0; ks < 4; ++ks)
            af[i][ks] = *(const bf16_8*)&As[rbuf][ra][((2 * ks + ah) ^ rx) * 8];
        }
      } else if (q == 1) {
        const int rb1 = (4 + wn) * 32 + am;
#pragma unroll
        for (int ks = 0; ks < 4; ++ks)
          bfr[1][ks] = *(const bf16_8*)&Bs[rbuf][rb1][((2 * ks + ah) ^ rx) * 8];
      } else if (q == 2) {
#pragma unroll
        for (int i = 0; i < 2; ++i) {
          const int ra = (4 + 2 * i + wm) * 32 + am;
#pragma unroll
          for (int ks = 0; ks < 4; ++ks)
            af[i][ks] = *(const bf16_8*)&As[rbuf][ra][((2 * ks + ah) ^ rx) * 8];
        }
      }
      // stage schedule (p compile-time; clamped dummies keep vmcnt math and
      // only overwrite regions already past their last read)
      if (p == 1) {
        int T = 2 * it + 2; if (T > NTILE - 1) T = NTILE - 1;
        STAGE(T, 0, 0); STAGE(T, 3, 0);
      } else if (p == 2) {
        int T = 2 * it + 2; if (T > NTILE - 1) T = NTILE - 1;
        STAGE(T, 1, 0);
      } else if (p == 3) {
        int T = 2 * it + 2; if (T > NTILE - 1) T = NTILE - 1;
        STAGE(T, 2, 0);
      } else if (p == 5) {
        int T = 2 * it + 3; if (T > NTILE - 1) T = NTILE - 1;
        STAGE(T, 0, 1); STAGE(T, 3, 1);
      } else if (p == 6) {
        int T = 2 * it + 3; if (T > NTILE - 1) T = NTILE - 1;
        STAGE(T, 1, 1);
      } else if (p == 7) {
        int T = 2 * it + 3; if (T > NTILE - 1) T = NTILE - 1;
        STAGE(T, 2, 1);
      }

      if (q == 3) asm volatile("s_waitcnt vmcnt(8)" ::: "memory");
      __builtin_amdgcn_s_barrier();
      if (q != 3) asm volatile("s_waitcnt lgkmcnt(0)" ::: "memory");
      __builtin_amdgcn_s_setprio(1);
#pragma unroll
      for (int ks = 0; ks < 4; ++ks)
#pragma unroll
        for (int i = 0; i < 2; ++i)
          acc[i0 + i][in] = __builtin_amdgcn_mfma_f32_32x32x16_bf16(
              af[i][ks], bfr[in][ks], acc[i0 + i][in], 0, 0, 0);
      __builtin_amdgcn_s_setprio(0);
      if (q == 3) {
        // prefetch next tile's B-h0 from the other buffer (just validated)
        const int rb0 = wn * 32 + am;
#pragma unroll
        for (int ks = 0; ks < 4; ++ks)
          bfr[0][ks] = *(const bf16_8*)&Bs[rbuf ^ 1][rb0][((2 * ks + ah) ^ rx) * 8];
      }
      __builtin_amdgcn_s_barrier();
    }
  }
  asm volatile("s_waitcnt vmcnt(0) lgkmcnt(0)" ::: "memory");  // drain dummies

  // C/D layout (32x32): col = lane&31, row = (reg&3) + 8*(reg>>2) + 4*(lane>>5)
  const int cc = am;
  const int rq = ah * 4;
#pragma unroll
  for (int im = 0; im < 4; ++im)
#pragma unroll
    for (int in = 0; in < 2; ++in)
#pragma unroll
      for (int reg = 0; reg < 16; ++reg) {
        int row = (reg & 3) + 8 * (reg >> 2) + rq;
        Cb[(size_t)(tm + (2 * im + wm) * 32 + row) * NN +
           (tn + (4 * in + wn) * 32 + cc)] = (__bf16)acc[im][in][reg];
      }

  if (Ctb != nullptr) {
    __syncthreads();
    __bf16 (*Tt)[264] = (__bf16(*)[264])smem;       // 64 x 264 x 2B = 33.8 KB
#pragma unroll
    for (int ch = 0; ch < 4; ++ch) {
      // chunk ch = C cols [ch*64, +64): writers have wn>>1 == ch&1, in = ch>>1
      if ((wn >> 1) == (ch & 1)) {
        const int inw = ch >> 1;
#pragma unroll
        for (int im = 0; im < 4; ++im)
#pragma unroll
          for (int g = 0; g < 4; ++g) {
            bf16_4 v;
#pragma unroll
            for (int r = 0; r < 4; ++r) v[r] = (__bf16)acc[im][inw][g * 4 + r];
            *(bf16_4*)&Tt[(wn & 1) * 32 + cc][(2 * im + wm) * 32 + 8 * g + rq] = v;
          }
      }
      __syncthreads();
#pragma unroll
      for (int rr = 0; rr < 4; ++rr) {
        int trow = rr * 16 + (tid >> 5);
        int tcol = (tid & 31) * 8;
        bf16_8 v = *(const bf16_8*)&Tt[trow][tcol];
        *(bf16_8*)&Ctb[(size_t)(tn + ch * 64 + trow) * NN + tm + tcol] = v;
      }
      __syncthreads();
    }
  }
#undef STAGE
}

// G1: A2 = A @ A (dual-write A2, A2t). 512 blocks = exactly 2 passes at
// 1 block/CU (128 KiB static LDS).
__global__ __launch_bounds__(512, 2)
void k_gemm1(const __bf16* __restrict__ Ab, const __bf16* __restrict__ At,
             __bf16* __restrict__ A2, __bf16* __restrict__ A2t) {
  __shared__ __align__(16) __bf16 smem[65536];  // 128 KB static
  size_t mb = (size_t)blockIdx.z * NN * NN;
  gemm_body256(Ab + mb, At + mb, A2 + mb, A2t + mb, smem, blockIdx.y, blockIdx.x);
}

// G2+G3 merged: z<8 -> A3t = At @ A2^T (single write); z>=8 -> A4 = A2 @ A2
// (dual-write A4, A4t). 1024 blocks = 4 passes.
__global__ __launch_bounds__(512, 2)
void k_gemm23(const __bf16* __restrict__ At, const __bf16* __restrict__ A2,
              const __bf16* __restrict__ A2t,
              __bf16* __restrict__ A3t, __bf16* __restrict__ A4,
              __bf16* __restrict__ A4t) {
  __shared__ __align__(16) __bf16 smem[65536];  // 128 KB static
  int job = blockIdx.z >> 3;
  size_t mb = (size_t)(blockIdx.z & 7) * NN * NN;
  if (job == 0)
    gemm_body256(At + mb, A2 + mb, A3t + mb, nullptr, smem, blockIdx.y, blockIdx.x);
  else
    gemm_body256(A2 + mb, A2t + mb, A4 + mb, A4t + mb, smem, blockIdx.y, blockIdx.x);
}

// One wave per row n. d5=row(A2)·row(A3t), d6=row(A2)·row(A4t),
// d7=row(A4)·row(A3t), d8=row(A4)·row(A4t). d1..d4 free diagonal reads.
__global__ __launch_bounds__(256)
void k_reduce(const float* __restrict__ A, const float* __restrict__ h,
              const __bf16* __restrict__ A2, const __bf16* __restrict__ A3t,
              const __bf16* __restrict__ A4, const __bf16* __restrict__ A4t,
              float* __restrict__ out) {
  int b = blockIdx.y;
  int wave = threadIdx.x >> 6, lane = threadIdx.x & 63;
  int n = blockIdx.x * 4 + wave;
  size_t mb = (size_t)b * NN * NN;
  size_t rb = mb + (size_t)n * NN;
  float d5 = 0, d6 = 0, d7 = 0, d8 = 0;
  for (int c = 0; c < NN; c += 512) {
    int k = c + lane * 8;
    bf16_8 va2  = *(const bf16_8*)(A2 + rb + k);
    bf16_8 va3t = *(const bf16_8*)(A3t + rb + k);
    bf16_8 va4  = *(const bf16_8*)(A4 + rb + k);
    bf16_8 va4t = *(const bf16_8*)(A4t + rb + k);
#pragma unroll
    for (int j = 0; j < 8; ++j) {
      float f2 = (float)va2[j], f4 = (float)va4[j];
      float f3t = (float)va3t[j], f4t = (float)va4t[j];
      d5 += f2 * f3t;
      d6 += f2 * f4t;
      d7 += f4 * f3t;
      d8 += f4 * f4t;
    }
  }
#pragma unroll
  for (int off = 32; off > 0; off >>= 1) {
    d5 += __shfl_xor(d5, off);
    d6 += __shfl_xor(d6, off);
    d7 += __shfl_xor(d7, off);
    d8 += __shfl_xor(d8, off);
  }
  float d1 = A[mb + (size_t)n * NN + n];
  float d2 = (float)A2[rb + n];
  float d3 = (float)A3t[rb + n];
  float d4 = (float)A4[rb + n];
  float r = h[lane] + h[64 + lane] * d1 + h[128 + lane] * d2 + h[192 + lane] * d3 +
            h[256 + lane] * d4 + h[320 + lane] * d5 + h[384 + lane] * d6 +
            h[448 + lane] * d7 + h[512 + lane] * d8;
  out[((size_t)b * NN + n) * NC + lane] = r;
}

extern "C" void kernel_launch(void* const* d_in, const int* in_sizes, int n_in,
                              void* d_out, int out_size, void* d_ws, size_t ws_size,
                              hipStream_t stream) {
  const float* A = (const float*)d_in[0];
  const float* h = (const float*)d_in[1];
  float* out = (float*)d_out;

  size_t elems = (size_t)BB * NN * NN;  // 64 MiB per bf16 buffer
  __bf16* Ab  = (__bf16*)d_ws;
  __bf16* At  = Ab + elems;
  __bf16* A2  = At + elems;
  __bf16* A2t = A2 + elems;
  __bf16* A3t = A2t + elems;
  __bf16* A4  = A3t + elems;
  __bf16* A4t = Ab;  // alias: Ab dead after G1 (total ws: 6 x 64 MiB)

  // A -> bf16 + transpose
  k_convert<<<dim3(32, 32, BB), dim3(256), 0, stream>>>(A, Ab, At);
  // A2 = A @ A  (dual-write)
  k_gemm1<<<dim3(8, 8, BB), dim3(512), 0, stream>>>(Ab, At, A2, A2t);
  // A3t = (A^3)^T and A4 = A2 @ A2 (+A4t) in one dispatch
  k_gemm23<<<dim3(8, 8, 2 * BB), dim3(512), 0, stream>>>(At, A2, A2t, A3t, A4, A4t);
  // diagonals + channel combine
  k_reduce<<<dim3(NN / 4, BB), dim3(256), 0, stream>>>(A, h, A2, A3t, A4, A4t, out);
}

// Round 5
// 660.923 us; speedup vs baseline: 1.0033x; 1.0033x over previous
//
#include <hip/hip_runtime.h>
#include <hip/hip_bf16.h>

#define NN 2048
#define BB 8
#define NC 64
#define NTILE 32   // K-tiles of 64
#define NITER 16   // 2 K-tiles per main-loop iteration

typedef __bf16 bf16_8 __attribute__((ext_vector_type(8)));
typedef __bf16 bf16_4 __attribute__((ext_vector_type(4)));
typedef float f32x16 __attribute__((ext_vector_type(16)));

__device__ __forceinline__ void gll16(const void* g, void* l) {
  __builtin_amdgcn_global_load_lds((const __attribute__((address_space(1))) void*)g,
                                   (__attribute__((address_space(3))) void*)l,
                                   16, 0, 0);
}

// fp32 -> bf16 convert + transpose, 16B/lane global reads. (unchanged)
__global__ __launch_bounds__(256)
void k_convert(const float* __restrict__ A, __bf16* __restrict__ Ab, __bf16* __restrict__ At) {
  __shared__ __bf16 tile[64][65];
  int b = blockIdx.z;
  const float* Asrc = A + (size_t)b * NN * NN;
  __bf16* Abd = Ab + (size_t)b * NN * NN;
  __bf16* Atd = At + (size_t)b * NN * NN;
  int r0 = blockIdx.y * 64, c0 = blockIdx.x * 64;
  int row = threadIdx.x >> 4;          // 0..15
  int col4 = (threadIdx.x & 15) * 4;   // 0..60
#pragma unroll
  for (int rr = 0; rr < 64; rr += 16) {
    float4 v = *(const float4*)&Asrc[(size_t)(r0 + row + rr) * NN + c0 + col4];
    bf16_4 hv;
    hv[0] = (__bf16)v.x; hv[1] = (__bf16)v.y; hv[2] = (__bf16)v.z; hv[3] = (__bf16)v.w;
    *(bf16_4*)&Abd[(size_t)(r0 + row + rr) * NN + c0 + col4] = hv;
    tile[row + rr][col4 + 0] = hv[0];
    tile[row + rr][col4 + 1] = hv[1];
    tile[row + rr][col4 + 2] = hv[2];
    tile[row + rr][col4 + 3] = hv[3];
  }
  __syncthreads();
  int row2 = threadIdx.x >> 3;         // 0..31
  int col8 = (threadIdx.x & 7) * 8;    // 0..56
#pragma unroll
  for (int rr = 0; rr < 64; rr += 32) {
    bf16_8 v;
#pragma unroll
    for (int j = 0; j < 8; ++j) v[j] = tile[col8 + j][row2 + rr];
    *(bf16_8*)&Atd[(size_t)(c0 + row2 + rr) * NN + r0 + col8] = v;
  }
}

// C[m,n] = sum_k P[m,k]*Q[n,k], one batch. 256x256 tile, BK=64, 8 waves
// (wm=wave>>2, wn=wave&3), 32x32x16 MFMA. Static 128 KiB LDS.
// Chunk swizzle g(r)=(r>>1)&7 (r4: conflict-free, -98% SQ_LDS_BANK_CONFLICT).
//
// TWO-PHASE K-tile (r4 post-mortem: 8 small phases -> 42% MfmaUtil across 3
// schedules; per-phase barrier+wait overhead with only 512 MFMA-cyc/SIMD to
// amortize. Merge to 2 regions/K-tile = 1024 MFMA-cyc/SIMD per barrier-pair;
// no explicit lgkmcnt -- compiler inserts exact counted waits, enabling
// read/MFMA overlap inside each region):
//   X(t): read A-h0(8) B0(4) B1(4) from buf b; stage A-h1(t+1)->buf nb (2);
//         16 MFMA acc[0..1][*]; sched_barrier(0); s_barrier
//   Y(t): read A-h1(8) from buf b; stage A-h0,B-h0,B-h1(t+2)->buf b (6);
//         16 MFMA acc[2..3][*]; vmcnt(6); sched_barrier(0); s_barrier
// WAR: A0/B0/B1 of buf b last read at X(t) -> overwritten at Y(t) (after X's
// end barrier; X's reads complete before it since their consuming MFMAs
// precede sched_barrier(0)). A-h1 last read Y(t-1) -> staged X(t). vmcnt(6)
// at Y(t) end waits X(t)'s 2 loads + older => tile t+1 fully landed for
// X(t+1); leaves Y(t)'s own 6 in flight. Never drains to 0 in the loop.
__device__ __forceinline__
void gemm_body256(const __bf16* __restrict__ Pb, const __bf16* __restrict__ Qb,
                  __bf16* __restrict__ Cb, __bf16* __restrict__ Ctb,
                  __bf16* smem, int tmBlk, int tnBlk) {
  __bf16 (*As)[256][64] = (__bf16(*)[256][64])smem;            // 2 x 32 KB
  __bf16 (*Bs)[256][64] = (__bf16(*)[256][64])(smem + 32768);  // 2 x 32 KB
  const int tid = threadIdx.x;
  const int wave = tid >> 6, lane = tid & 63;
  const int wm = wave >> 2, wn = wave & 3;
  const int tm = tmBlk * 256, tn = tnBlk * 256;
  const int am = lane & 31, ah = lane >> 5;
  const int rx = (am >> 1) & 7;   // read-side swizzle g(row)=(row>>1)&7

  // staging geometry: wave covers 8 rows/chunk; LDS dest linear (lane*16B).
  // Source chunk pre-swizzled: physical chunk p = lane&7 at row
  // base+wave*8+(lane>>3) holds logical chunk p ^ g(row);
  // g(row) = (row>>1)&7 = ((wave&1)*4 + (lane>>4)) & 7 here.
  const int sr = lane >> 3;
  const int sc = (lane & 7) ^ (((wave & 1) * 4 + (lane >> 4)) & 7);
  const __bf16* srcA = Pb + (size_t)(tm + wave * 8 + sr) * NN + sc * 8;
  const __bf16* srcB = Qb + (size_t)(tn + wave * 8 + sr) * NN + sc * 8;

#define STAGE(Tc_, s_, bufT_)                                                  \
  do {                                                                         \
    if ((s_) == 0) { /* A h0 */                                                \
      const __bf16* s0 = srcA + (size_t)(Tc_) * 64;                            \
      gll16(s0,                   &As[bufT_][wave * 8][0]);                    \
      gll16(s0 + (size_t)64 * NN, &As[bufT_][64 + wave * 8][0]);               \
    } else if ((s_) == 1) { /* B h1 */                                         \
      const __bf16* s0 = srcB + (size_t)128 * NN + (size_t)(Tc_) * 64;         \
      gll16(s0,                   &Bs[bufT_][128 + wave * 8][0]);              \
      gll16(s0 + (size_t)64 * NN, &Bs[bufT_][192 + wave * 8][0]);              \
    } else if ((s_) == 2) { /* A h1 */                                         \
      const __bf16* s0 = srcA + (size_t)128 * NN + (size_t)(Tc_) * 64;         \
      gll16(s0,                   &As[bufT_][128 + wave * 8][0]);              \
      gll16(s0 + (size_t)64 * NN, &As[bufT_][192 + wave * 8][0]);              \
    } else { /* B h0 */                                                        \
      const __bf16* s0 = srcB + (size_t)(Tc_) * 64;                            \
      gll16(s0,                   &Bs[bufT_][wave * 8][0]);                    \
      gll16(s0 + (size_t)64 * NN, &Bs[bufT_][64 + wave * 8][0]);               \
    }                                                                          \
  } while (0)

  // prologue: tile0 full (8 loads, plays Y(-2)+X(-1)), tile1 A0/B0/B1
  // (6 loads, plays Y(-1)). vmcnt(6) -> tile0 fully landed.
  STAGE(0, 0, 0); STAGE(0, 3, 0); STAGE(0, 1, 0); STAGE(0, 2, 0);
  STAGE(1, 0, 1); STAGE(1, 3, 1); STAGE(1, 1, 1);
  asm volatile("s_waitcnt vmcnt(6)" ::: "memory");
  __builtin_amdgcn_s_barrier();

  f32x16 acc[4][2] = {};
  bf16_8 af[2][4], bfr[2][4];

  for (int it = 0; it < NITER; ++it) {
#pragma unroll
    for (int h = 0; h < 2; ++h) {     // K-tile t = 2*it + h, buf b = h
      const int b = h;
      // ================= X phase =================
      // reads: A-h0 interleaved with B0 so the first MFMA chain is ready
      // after 8 reads; B1 last.
#pragma unroll
      for (int ks = 0; ks < 4; ++ks) {
        const int ra = (0 * 2 + wm) * 32 + am;   // im=0 rows
        af[0][ks] = *(const bf16_8*)&As[b][ra][((2 * ks + ah) ^ rx) * 8];
      }
#pragma unroll
      for (int ks = 0; ks < 4; ++ks) {
        const int rb0 = wn * 32 + am;
        bfr[0][ks] = *(const bf16_8*)&Bs[b][rb0][((2 * ks + ah) ^ rx) * 8];
      }
#pragma unroll
      for (int ks = 0; ks < 4; ++ks) {
        const int ra = (1 * 2 + wm) * 32 + am;   // im=1 rows
        af[1][ks] = *(const bf16_8*)&As[b][ra][((2 * ks + ah) ^ rx) * 8];
      }
#pragma unroll
      for (int ks = 0; ks < 4; ++ks) {
        const int rb1 = (4 + wn) * 32 + am;
        bfr[1][ks] = *(const bf16_8*)&Bs[b][rb1][((2 * ks + ah) ^ rx) * 8];
      }
      // stage: A-h1 of tile t+1 -> other buffer (last read Y(t-1))
      {
        int T = 2 * it + h + 1; if (T > NTILE - 1) T = NTILE - 1;
        STAGE(T, 2, b ^ 1);
      }
      __builtin_amdgcn_s_setprio(1);
#pragma unroll
      for (int ks = 0; ks < 4; ++ks) {
#pragma unroll
        for (int i = 0; i < 2; ++i) {
          acc[i][0] = __builtin_amdgcn_mfma_f32_32x32x16_bf16(
              af[i][ks], bfr[0][ks], acc[i][0], 0, 0, 0);
          acc[i][1] = __builtin_amdgcn_mfma_f32_32x32x16_bf16(
              af[i][ks], bfr[1][ks], acc[i][1], 0, 0, 0);
        }
      }
      __builtin_amdgcn_s_setprio(0);
      __builtin_amdgcn_sched_barrier(0);
      __builtin_amdgcn_s_barrier();
      // ================= Y phase =================
      // reads: A-h1 (af regs reused; A-h0 values dead after X's MFMAs)
#pragma unroll
      for (int i = 0; i < 2; ++i) {
        const int ra = (4 + 2 * i + wm) * 32 + am;
#pragma unroll
        for (int ks = 0; ks < 4; ++ks)
          af[i][ks] = *(const bf16_8*)&As[b][ra][((2 * ks + ah) ^ rx) * 8];
      }
      // stage: A-h0/B-h0/B-h1 of tile t+2 -> this buffer (last read X(t))
      {
        int T = 2 * it + h + 2; if (T > NTILE - 1) T = NTILE - 1;
        STAGE(T, 0, b); STAGE(T, 3, b); STAGE(T, 1, b);
      }
      __builtin_amdgcn_s_setprio(1);
#pragma unroll
      for (int ks = 0; ks < 4; ++ks) {
#pragma unroll
        for (int i = 0; i < 2; ++i) {
          acc[2 + i][1] = __builtin_amdgcn_mfma_f32_32x32x16_bf16(
              af[i][ks], bfr[1][ks], acc[2 + i][1], 0, 0, 0);
          acc[2 + i][0] = __builtin_amdgcn_mfma_f32_32x32x16_bf16(
              af[i][ks], bfr[0][ks], acc[2 + i][0], 0, 0, 0);
        }
      }
      __builtin_amdgcn_s_setprio(0);
      // validate tile t+1 for next X: waits X(t)'s 2 loads and older,
      // leaves this Y's 6 in flight.
      asm volatile("s_waitcnt vmcnt(6)" ::: "memory");
      __builtin_amdgcn_sched_barrier(0);
      __builtin_amdgcn_s_barrier();
    }
  }
  asm volatile("s_waitcnt vmcnt(0) lgkmcnt(0)" ::: "memory");  // drain dummies

  // C/D layout (32x32): col = lane&31, row = (reg&3) + 8*(reg>>2) + 4*(lane>>5)
  const int cc = am;
  const int rq = ah * 4;
#pragma unroll
  for (int im = 0; im < 4; ++im)
#pragma unroll
    for (int in = 0; in < 2; ++in)
#pragma unroll
      for (int reg = 0; reg < 16; ++reg) {
        int row = (reg & 3) + 8 * (reg >> 2) + rq;
        Cb[(size_t)(tm + (2 * im + wm) * 32 + row) * NN +
           (tn + (4 * in + wn) * 32 + cc)] = (__bf16)acc[im][in][reg];
      }

  if (Ctb != nullptr) {
    __syncthreads();
    __bf16 (*Tt)[264] = (__bf16(*)[264])smem;       // 64 x 264 x 2B = 33.8 KB
#pragma unroll
    for (int ch = 0; ch < 4; ++ch) {
      // chunk ch = C cols [ch*64, +64): writers have wn>>1 == ch&1, in = ch>>1
      if ((wn >> 1) == (ch & 1)) {
        const int inw = ch >> 1;
#pragma unroll
        for (int im = 0; im < 4; ++im)
#pragma unroll
          for (int g = 0; g < 4; ++g) {
            bf16_4 v;
#pragma unroll
            for (int r = 0; r < 4; ++r) v[r] = (__bf16)acc[im][inw][g * 4 + r];
            *(bf16_4*)&Tt[(wn & 1) * 32 + cc][(2 * im + wm) * 32 + 8 * g + rq] = v;
          }
      }
      __syncthreads();
#pragma unroll
      for (int rr = 0; rr < 4; ++rr) {
        int trow = rr * 16 + (tid >> 5);
        int tcol = (tid & 31) * 8;
        bf16_8 v = *(const bf16_8*)&Tt[trow][tcol];
        *(bf16_8*)&Ctb[(size_t)(tn + ch * 64 + trow) * NN + tm + tcol] = v;
      }
      __syncthreads();
    }
  }
#undef STAGE
}

// G1: A2 = A @ A (dual-write A2, A2t). 512 blocks = exactly 2 passes at
// 1 block/CU (128 KiB static LDS).
__global__ __launch_bounds__(512, 2)
void k_gemm1(const __bf16* __restrict__ Ab, const __bf16* __restrict__ At,
             __bf16* __restrict__ A2, __bf16* __restrict__ A2t) {
  __shared__ __align__(16) __bf16 smem[65536];  // 128 KB static
  size_t mb = (size_t)blockIdx.z * NN * NN;
  gemm_body256(Ab + mb, At + mb, A2 + mb, A2t + mb, smem, blockIdx.y, blockIdx.x);
}

// G2+G3 merged: z<8 -> A3t = At @ A2^T (single write); z>=8 -> A4 = A2 @ A2
// (dual-write A4, A4t). 1024 blocks = 4 passes.
__global__ __launch_bounds__(512, 2)
void k_gemm23(const __bf16* __restrict__ At, const __bf16* __restrict__ A2,
              const __bf16* __restrict__ A2t,
              __bf16* __restrict__ A3t, __bf16* __restrict__ A4,
              __bf16* __restrict__ A4t) {
  __shared__ __align__(16) __bf16 smem[65536];  // 128 KB static
  int job = blockIdx.z >> 3;
  size_t mb = (size_t)(blockIdx.z & 7) * NN * NN;
  if (job == 0)
    gemm_body256(At + mb, A2 + mb, A3t + mb, nullptr, smem, blockIdx.y, blockIdx.x);
  else
    gemm_body256(A2 + mb, A2t + mb, A4 + mb, A4t + mb, smem, blockIdx.y, blockIdx.x);
}

// One wave per row n. d5=row(A2)·row(A3t), d6=row(A2)·row(A4t),
// d7=row(A4)·row(A3t), d8=row(A4)·row(A4t). d1..d4 free diagonal reads.
__global__ __launch_bounds__(256)
void k_reduce(const float* __restrict__ A, const float* __restrict__ h,
              const __bf16* __restrict__ A2, const __bf16* __restrict__ A3t,
              const __bf16* __restrict__ A4, const __bf16* __restrict__ A4t,
              float* __restrict__ out) {
  int b = blockIdx.y;
  int wave = threadIdx.x >> 6, lane = threadIdx.x & 63;
  int n = blockIdx.x * 4 + wave;
  size_t mb = (size_t)b * NN * NN;
  size_t rb = mb + (size_t)n * NN;
  float d5 = 0, d6 = 0, d7 = 0, d8 = 0;
  for (int c = 0; c < NN; c += 512) {
    int k = c + lane * 8;
    bf16_8 va2  = *(const bf16_8*)(A2 + rb + k);
    bf16_8 va3t = *(const bf16_8*)(A3t + rb + k);
    bf16_8 va4  = *(const bf16_8*)(A4 + rb + k);
    bf16_8 va4t = *(const bf16_8*)(A4t + rb + k);
#pragma unroll
    for (int j = 0; j < 8; ++j) {
      float f2 = (float)va2[j], f4 = (float)va4[j];
      float f3t = (float)va3t[j], f4t = (float)va4t[j];
      d5 += f2 * f3t;
      d6 += f2 * f4t;
      d7 += f4 * f3t;
      d8 += f4 * f4t;
    }
  }
#pragma unroll
  for (int off = 32; off > 0; off >>= 1) {
    d5 += __shfl_xor(d5, off);
    d6 += __shfl_xor(d6, off);
    d7 += __shfl_xor(d7, off);
    d8 += __shfl_xor(d8, off);
  }
  float d1 = A[mb + (size_t)n * NN + n];
  float d2 = (float)A2[rb + n];
  float d3 = (float)A3t[rb + n];
  float d4 = (float)A4[rb + n];
  float r = h[lane] + h[64 + lane] * d1 + h[128 + lane] * d2 + h[192 + lane] * d3 +
            h[256 + lane] * d4 + h[320 + lane] * d5 + h[384 + lane] * d6 +
            h[448 + lane] * d7 + h[512 + lane] * d8;
  out[((size_t)b * NN + n) * NC + lane] = r;
}

extern "C" void kernel_launch(void* const* d_in, const int* in_sizes, int n_in,
                              void* d_out, int out_size, void* d_ws, size_t ws_size,
                              hipStream_t stream) {
  const float* A = (const float*)d_in[0];
  const float* h = (const float*)d_in[1];
  float* out = (float*)d_out;

  size_t elems = (size_t)BB * NN * NN;  // 64 MiB per bf16 buffer
  __bf16* Ab  = (__bf16*)d_ws;
  __bf16* At  = Ab + elems;
  __bf16* A2  = At + elems;
  __bf16* A2t = A2 + elems;
  __bf16* A3t = A2t + elems;
  __bf16* A4  = A3t + elems;
  __bf16* A4t = Ab;  // alias: Ab dead after G1 (total ws: 6 x 64 MiB)

  // A -> bf16 + transpose
  k_convert<<<dim3(32, 32, BB), dim3(256), 0, stream>>>(A, Ab, At);
  // A2 = A @ A  (dual-write)
  k_gemm1<<<dim3(8, 8, BB), dim3(512), 0, stream>>>(Ab, At, A2, A2t);
  // A3t = (A^3)^T and A4 = A2 @ A2 (+A4t) in one dispatch
  k_gemm23<<<dim3(8, 8, 2 * BB), dim3(512), 0, stream>>>(At, A2, A2t, A3t, A4, A4t);
  // diagonals + channel combine
  k_reduce<<<dim3(NN / 4, BB), dim3(256), 0, stream>>>(A, h, A2, A3t, A4, A4t, out);
}

// Round 6
// 645.517 us; speedup vs baseline: 1.0272x; 1.0239x over previous
//
#include <hip/hip_runtime.h>
#include <hip/hip_bf16.h>

#define NN 2048
#define BB 8
#define NC 64
#define NTILE 32   // K-tiles of 64
#define NITER 16   // 2 K-tiles per main-loop iteration

typedef __bf16 bf16_8 __attribute__((ext_vector_type(8)));
typedef __bf16 bf16_4 __attribute__((ext_vector_type(4)));
typedef float f32x16 __attribute__((ext_vector_type(16)));

__device__ __forceinline__ void gll16(const void* g, void* l) {
  __builtin_amdgcn_global_load_lds((const __attribute__((address_space(1))) void*)g,
                                   (__attribute__((address_space(3))) void*)l,
                                   16, 0, 0);
}

// fp32 -> bf16 convert + transpose, 16B/lane global reads. (unchanged)
__global__ __launch_bounds__(256)
void k_convert(const float* __restrict__ A, __bf16* __restrict__ Ab, __bf16* __restrict__ At) {
  __shared__ __bf16 tile[64][65];
  int b = blockIdx.z;
  const float* Asrc = A + (size_t)b * NN * NN;
  __bf16* Abd = Ab + (size_t)b * NN * NN;
  __bf16* Atd = At + (size_t)b * NN * NN;
  int r0 = blockIdx.y * 64, c0 = blockIdx.x * 64;
  int row = threadIdx.x >> 4;          // 0..15
  int col4 = (threadIdx.x & 15) * 4;   // 0..60
#pragma unroll
  for (int rr = 0; rr < 64; rr += 16) {
    float4 v = *(const float4*)&Asrc[(size_t)(r0 + row + rr) * NN + c0 + col4];
    bf16_4 hv;
    hv[0] = (__bf16)v.x; hv[1] = (__bf16)v.y; hv[2] = (__bf16)v.z; hv[3] = (__bf16)v.w;
    *(bf16_4*)&Abd[(size_t)(r0 + row + rr) * NN + c0 + col4] = hv;
    tile[row + rr][col4 + 0] = hv[0];
    tile[row + rr][col4 + 1] = hv[1];
    tile[row + rr][col4 + 2] = hv[2];
    tile[row + rr][col4 + 3] = hv[3];
  }
  __syncthreads();
  int row2 = threadIdx.x >> 3;         // 0..31
  int col8 = (threadIdx.x & 7) * 8;    // 0..56
#pragma unroll
  for (int rr = 0; rr < 64; rr += 32) {
    bf16_8 v;
#pragma unroll
    for (int j = 0; j < 8; ++j) v[j] = tile[col8 + j][row2 + rr];
    *(bf16_8*)&Atd[(size_t)(c0 + row2 + rr) * NN + r0 + col8] = v;
  }
}

// C[m,n] = sum_k P[m,k]*Q[n,k], one batch. 256x256 tile, BK=64, 8 waves
// (wm=wave>>2, wn=wave&3), 32x32x16 MFMA. Static 128 KiB LDS.
// Chunk swizzle g(r)=(r>>1)&7 (r4: conflict-free, -98% SQ_LDS_BANK_CONFLICT).
// Two-phase K-tile schedule (r5; equals 8-phase perf, kept for fewer syncs).
__device__ __forceinline__
void gemm_body256(const __bf16* __restrict__ Pb, const __bf16* __restrict__ Qb,
                  __bf16* __restrict__ Cb, __bf16* __restrict__ Ctb,
                  __bf16* smem, int tmBlk, int tnBlk) {
  __bf16 (*As)[256][64] = (__bf16(*)[256][64])smem;            // 2 x 32 KB
  __bf16 (*Bs)[256][64] = (__bf16(*)[256][64])(smem + 32768);  // 2 x 32 KB
  const int tid = threadIdx.x;
  const int wave = tid >> 6, lane = tid & 63;
  const int wm = wave >> 2, wn = wave & 3;
  const int tm = tmBlk * 256, tn = tnBlk * 256;
  const int am = lane & 31, ah = lane >> 5;
  const int rx = (am >> 1) & 7;   // read-side swizzle g(row)=(row>>1)&7

  const int sr = lane >> 3;
  const int sc = (lane & 7) ^ (((wave & 1) * 4 + (lane >> 4)) & 7);
  const __bf16* srcA = Pb + (size_t)(tm + wave * 8 + sr) * NN + sc * 8;
  const __bf16* srcB = Qb + (size_t)(tn + wave * 8 + sr) * NN + sc * 8;

#define STAGE(Tc_, s_, bufT_)                                                  \
  do {                                                                         \
    if ((s_) == 0) { /* A h0 */                                                \
      const __bf16* s0 = srcA + (size_t)(Tc_) * 64;                            \
      gll16(s0,                   &As[bufT_][wave * 8][0]);                    \
      gll16(s0 + (size_t)64 * NN, &As[bufT_][64 + wave * 8][0]);               \
    } else if ((s_) == 1) { /* B h1 */                                         \
      const __bf16* s0 = srcB + (size_t)128 * NN + (size_t)(Tc_) * 64;         \
      gll16(s0,                   &Bs[bufT_][128 + wave * 8][0]);              \
      gll16(s0 + (size_t)64 * NN, &Bs[bufT_][192 + wave * 8][0]);              \
    } else if ((s_) == 2) { /* A h1 */                                         \
      const __bf16* s0 = srcA + (size_t)128 * NN + (size_t)(Tc_) * 64;         \
      gll16(s0,                   &As[bufT_][128 + wave * 8][0]);              \
      gll16(s0 + (size_t)64 * NN, &As[bufT_][192 + wave * 8][0]);              \
    } else { /* B h0 */                                                        \
      const __bf16* s0 = srcB + (size_t)(Tc_) * 64;                            \
      gll16(s0,                   &Bs[bufT_][wave * 8][0]);                    \
      gll16(s0 + (size_t)64 * NN, &Bs[bufT_][64 + wave * 8][0]);               \
    }                                                                          \
  } while (0)

  // prologue: tile0 full (8 loads), tile1 A0/B0/B1 (6 loads).
  STAGE(0, 0, 0); STAGE(0, 3, 0); STAGE(0, 1, 0); STAGE(0, 2, 0);
  STAGE(1, 0, 1); STAGE(1, 3, 1); STAGE(1, 1, 1);
  asm volatile("s_waitcnt vmcnt(6)" ::: "memory");
  __builtin_amdgcn_s_barrier();

  f32x16 acc[4][2] = {};
  bf16_8 af[2][4], bfr[2][4];

  for (int it = 0; it < NITER; ++it) {
#pragma unroll
    for (int h = 0; h < 2; ++h) {     // K-tile t = 2*it + h, buf b = h
      const int b = h;
      // ================= X phase =================
#pragma unroll
      for (int ks = 0; ks < 4; ++ks) {
        const int ra = (0 * 2 + wm) * 32 + am;   // im=0 rows
        af[0][ks] = *(const bf16_8*)&As[b][ra][((2 * ks + ah) ^ rx) * 8];
      }
#pragma unroll
      for (int ks = 0; ks < 4; ++ks) {
        const int rb0 = wn * 32 + am;
        bfr[0][ks] = *(const bf16_8*)&Bs[b][rb0][((2 * ks + ah) ^ rx) * 8];
      }
#pragma unroll
      for (int ks = 0; ks < 4; ++ks) {
        const int ra = (1 * 2 + wm) * 32 + am;   // im=1 rows
        af[1][ks] = *(const bf16_8*)&As[b][ra][((2 * ks + ah) ^ rx) * 8];
      }
#pragma unroll
      for (int ks = 0; ks < 4; ++ks) {
        const int rb1 = (4 + wn) * 32 + am;
        bfr[1][ks] = *(const bf16_8*)&Bs[b][rb1][((2 * ks + ah) ^ rx) * 8];
      }
      // stage: A-h1 of tile t+1 -> other buffer (last read Y(t-1))
      {
        int T = 2 * it + h + 1; if (T > NTILE - 1) T = NTILE - 1;
        STAGE(T, 2, b ^ 1);
      }
      __builtin_amdgcn_s_setprio(1);
#pragma unroll
      for (int ks = 0; ks < 4; ++ks) {
#pragma unroll
        for (int i = 0; i < 2; ++i) {
          acc[i][0] = __builtin_amdgcn_mfma_f32_32x32x16_bf16(
              af[i][ks], bfr[0][ks], acc[i][0], 0, 0, 0);
          acc[i][1] = __builtin_amdgcn_mfma_f32_32x32x16_bf16(
              af[i][ks], bfr[1][ks], acc[i][1], 0, 0, 0);
        }
      }
      __builtin_amdgcn_s_setprio(0);
      __builtin_amdgcn_sched_barrier(0);
      __builtin_amdgcn_s_barrier();
      // ================= Y phase =================
#pragma unroll
      for (int i = 0; i < 2; ++i) {
        const int ra = (4 + 2 * i + wm) * 32 + am;
#pragma unroll
        for (int ks = 0; ks < 4; ++ks)
          af[i][ks] = *(const bf16_8*)&As[b][ra][((2 * ks + ah) ^ rx) * 8];
      }
      // stage: A-h0/B-h0/B-h1 of tile t+2 -> this buffer (last read X(t))
      {
        int T = 2 * it + h + 2; if (T > NTILE - 1) T = NTILE - 1;
        STAGE(T, 0, b); STAGE(T, 3, b); STAGE(T, 1, b);
      }
      __builtin_amdgcn_s_setprio(1);
#pragma unroll
      for (int ks = 0; ks < 4; ++ks) {
#pragma unroll
        for (int i = 0; i < 2; ++i) {
          acc[2 + i][1] = __builtin_amdgcn_mfma_f32_32x32x16_bf16(
              af[i][ks], bfr[1][ks], acc[2 + i][1], 0, 0, 0);
          acc[2 + i][0] = __builtin_amdgcn_mfma_f32_32x32x16_bf16(
              af[i][ks], bfr[0][ks], acc[2 + i][0], 0, 0, 0);
        }
      }
      __builtin_amdgcn_s_setprio(0);
      asm volatile("s_waitcnt vmcnt(6)" ::: "memory");
      __builtin_amdgcn_sched_barrier(0);
      __builtin_amdgcn_s_barrier();
    }
  }
  asm volatile("s_waitcnt vmcnt(0) lgkmcnt(0)" ::: "memory");  // drain dummies

  // C/D layout (32x32): col = lane&31, row = (reg&3) + 8*(reg>>2) + 4*(lane>>5)
  const int cc = am;
  const int rq = ah * 4;
#pragma unroll
  for (int im = 0; im < 4; ++im)
#pragma unroll
    for (int in = 0; in < 2; ++in)
#pragma unroll
      for (int reg = 0; reg < 16; ++reg) {
        int row = (reg & 3) + 8 * (reg >> 2) + rq;
        Cb[(size_t)(tm + (2 * im + wm) * 32 + row) * NN +
           (tn + (4 * in + wn) * 32 + cc)] = (__bf16)acc[im][in][reg];
      }

  if (Ctb != nullptr) {
    __syncthreads();
    __bf16 (*Tt)[264] = (__bf16(*)[264])smem;       // 64 x 264 x 2B = 33.8 KB
#pragma unroll
    for (int ch = 0; ch < 4; ++ch) {
      // chunk ch = C cols [ch*64, +64): writers have wn>>1 == ch&1, in = ch>>1
      if ((wn >> 1) == (ch & 1)) {
        const int inw = ch >> 1;
#pragma unroll
        for (int im = 0; im < 4; ++im)
#pragma unroll
          for (int g = 0; g < 4; ++g) {
            bf16_4 v;
#pragma unroll
            for (int r = 0; r < 4; ++r) v[r] = (__bf16)acc[im][inw][g * 4 + r];
            *(bf16_4*)&Tt[(wn & 1) * 32 + cc][(2 * im + wm) * 32 + 8 * g + rq] = v;
          }
      }
      __syncthreads();
#pragma unroll
      for (int rr = 0; rr < 4; ++rr) {
        int trow = rr * 16 + (tid >> 5);
        int tcol = (tid & 31) * 8;
        bf16_8 v = *(const bf16_8*)&Tt[trow][tcol];
        *(bf16_8*)&Ctb[(size_t)(tn + ch * 64 + trow) * NN + tm + tcol] = v;
      }
      __syncthreads();
    }
  }
#undef STAGE
}

// XCD-aware chunked swizzle (T1). HW assigns workgroups to XCDs round-robin
// on dispatch-linear id (lid % 8). Remap so each XCD owns a CONTIGUOUS tile
// range: swz = (lid%8)*(n/8) + lid/8 (bijective; n % 8 == 0 here).
// k_gemm1 (n=512): XCD r owns exactly batch r's whole GEMM.
// k_gemm23 (n=1024): XCD r owns jobs 2r,2r+1. Within a job, its 32 CUs run 4
// consecutive tm-rows: A-panels L2-resident (8 blocks share), B-panels shared
// by 4 concurrent rows -> L2-hit staging, shorter vmcnt round-trip.

// G1: A2 = A @ A (dual-write A2, A2t). 512 blocks = exactly 2 passes at
// 1 block/CU (128 KiB static LDS).
__global__ __launch_bounds__(512, 2)
void k_gemm1(const __bf16* __restrict__ Ab, const __bf16* __restrict__ At,
             __bf16* __restrict__ A2, __bf16* __restrict__ A2t) {
  __shared__ __align__(16) __bf16 smem[65536];  // 128 KB static
  int lid = ((int)blockIdx.z * gridDim.y + blockIdx.y) * gridDim.x + blockIdx.x;
  int swz = (lid & 7) * 64 + (lid >> 3);        // 512 blocks
  int bz = swz >> 6, ty = (swz >> 3) & 7, tx = swz & 7;
  size_t mb = (size_t)bz * NN * NN;
  gemm_body256(Ab + mb, At + mb, A2 + mb, A2t + mb, smem, ty, tx);
}

// G2+G3 merged: job0 -> A3t = At @ A2^T (single write); job1 -> A4 = A2 @ A2
// (dual-write A4, A4t). 1024 blocks = 4 passes.
__global__ __launch_bounds__(512, 2)
void k_gemm23(const __bf16* __restrict__ At, const __bf16* __restrict__ A2,
              const __bf16* __restrict__ A2t,
              __bf16* __restrict__ A3t, __bf16* __restrict__ A4,
              __bf16* __restrict__ A4t) {
  __shared__ __align__(16) __bf16 smem[65536];  // 128 KB static
  int lid = ((int)blockIdx.z * gridDim.y + blockIdx.y) * gridDim.x + blockIdx.x;
  int swz = (lid & 7) * 128 + (lid >> 3);       // 1024 blocks
  int bz = swz >> 6, ty = (swz >> 3) & 7, tx = swz & 7;
  int job = bz >> 3;
  size_t mb = (size_t)(bz & 7) * NN * NN;
  if (job == 0)
    gemm_body256(At + mb, A2 + mb, A3t + mb, nullptr, smem, ty, tx);
  else
    gemm_body256(A2 + mb, A2t + mb, A4 + mb, A4t + mb, smem, ty, tx);
}

// One wave per row n. d5=row(A2)·row(A3t), d6=row(A2)·row(A4t),
// d7=row(A4)·row(A3t), d8=row(A4)·row(A4t). d1..d4 free diagonal reads.
__global__ __launch_bounds__(256)
void k_reduce(const float* __restrict__ A, const float* __restrict__ h,
              const __bf16* __restrict__ A2, const __bf16* __restrict__ A3t,
              const __bf16* __restrict__ A4, const __bf16* __restrict__ A4t,
              float* __restrict__ out) {
  int b = blockIdx.y;
  int wave = threadIdx.x >> 6, lane = threadIdx.x & 63;
  int n = blockIdx.x * 4 + wave;
  size_t mb = (size_t)b * NN * NN;
  size_t rb = mb + (size_t)n * NN;
  float d5 = 0, d6 = 0, d7 = 0, d8 = 0;
  for (int c = 0; c < NN; c += 512) {
    int k = c + lane * 8;
    bf16_8 va2  = *(const bf16_8*)(A2 + rb + k);
    bf16_8 va3t = *(const bf16_8*)(A3t + rb + k);
    bf16_8 va4  = *(const bf16_8*)(A4 + rb + k);
    bf16_8 va4t = *(const bf16_8*)(A4t + rb + k);
#pragma unroll
    for (int j = 0; j < 8; ++j) {
      float f2 = (float)va2[j], f4 = (float)va4[j];
      float f3t = (float)va3t[j], f4t = (float)va4t[j];
      d5 += f2 * f3t;
      d6 += f2 * f4t;
      d7 += f4 * f3t;
      d8 += f4 * f4t;
    }
  }
#pragma unroll
  for (int off = 32; off > 0; off >>= 1) {
    d5 += __shfl_xor(d5, off);
    d6 += __shfl_xor(d6, off);
    d7 += __shfl_xor(d7, off);
    d8 += __shfl_xor(d8, off);
  }
  float d1 = A[mb + (size_t)n * NN + n];
  float d2 = (float)A2[rb + n];
  float d3 = (float)A3t[rb + n];
  float d4 = (float)A4[rb + n];
  float r = h[lane] + h[64 + lane] * d1 + h[128 + lane] * d2 + h[192 + lane] * d3 +
            h[256 + lane] * d4 + h[320 + lane] * d5 + h[384 + lane] * d6 +
            h[448 + lane] * d7 + h[512 + lane] * d8;
  out[((size_t)b * NN + n) * NC + lane] = r;
}

extern "C" void kernel_launch(void* const* d_in, const int* in_sizes, int n_in,
                              void* d_out, int out_size, void* d_ws, size_t ws_size,
                              hipStream_t stream) {
  const float* A = (const float*)d_in[0];
  const float* h = (const float*)d_in[1];
  float* out = (float*)d_out;

  size_t elems = (size_t)BB * NN * NN;  // 64 MiB per bf16 buffer
  __bf16* Ab  = (__bf16*)d_ws;
  __bf16* At  = Ab + elems;
  __bf16* A2  = At + elems;
  __bf16* A2t = A2 + elems;
  __bf16* A3t = A2t + elems;
  __bf16* A4  = A3t + elems;
  __bf16* A4t = Ab;  // alias: Ab dead after G1 (total ws: 6 x 64 MiB)

  // A -> bf16 + transpose
  k_convert<<<dim3(32, 32, BB), dim3(256), 0, stream>>>(A, Ab, At);
  // A2 = A @ A  (dual-write)
  k_gemm1<<<dim3(8, 8, BB), dim3(512), 0, stream>>>(Ab, At, A2, A2t);
  // A3t = (A^3)^T and A4 = A2 @ A2 (+A4t) in one dispatch
  k_gemm23<<<dim3(8, 8, 2 * BB), dim3(512), 0, stream>>>(At, A2, A2t, A3t, A4, A4t);
  // diagonals + channel combine
  k_reduce<<<dim3(NN / 4, BB), dim3(256), 0, stream>>>(A, h, A2, A3t, A4, A4t, out);
}